// Round 5
// baseline (322.519 us; speedup 1.0000x reference)
//
#include <hip/hip_runtime.h>

#define S_DIM 2048
#define K_DIM 4096
#define O_DIM 4096
#define NNON  3968   // H - KEEPER
#define NB    31     // low-precision blocks

#define XBLK 8192    // scale_x segment blocks:  S*K/4/256
#define WBLK 16384   // scale_w segment blocks:  O*K/4/256

typedef __bf16 bf16x8 __attribute__((ext_vector_type(8)));
typedef float  f32x4  __attribute__((ext_vector_type(4)));

__device__ __forceinline__ unsigned short f2bf(float f) {
    union { float f; unsigned u; } v; v.f = f;
    unsigned r = v.u + 0x7FFFu + ((v.u >> 16) & 1u);   // round-to-nearest-even
    return (unsigned short)(r >> 16);
}

// One fused prepass launch, two block-uniform segments:
//   [0, XBLK)           A'[s,k] = bf16(x * sc_lo/hi)
//   [XBLK, XBLK+WBLK)   B'[o,k] = bf16(w * scales/keep)
__global__ __launch_bounds__(256) void prepass(const float* __restrict__ x,
                                               const float* __restrict__ sc_lo,
                                               const float* __restrict__ sc_hi,
                                               const float* __restrict__ w,
                                               const float* __restrict__ scales,
                                               const float* __restrict__ keep,
                                               unsigned short* __restrict__ A,
                                               unsigned short* __restrict__ B)
{
    const int b = blockIdx.x;
    if (b < XBLK) {
        int idx = b * 256 + threadIdx.x;           // over S*K/4, K/4 = 1024
        int s = idx >> 10;
        int k = (idx & 1023) << 2;                 // 4 elems never straddle a 128-block
        float4 v = ((const float4*)x)[idx];
        float sc = (k < NNON) ? sc_lo[s * NB + (k >> 7)] : sc_hi[s];
        ushort4 o;
        o.x = f2bf(v.x * sc); o.y = f2bf(v.y * sc);
        o.z = f2bf(v.z * sc); o.w = f2bf(v.w * sc);
        ((ushort4*)A)[idx] = o;
    } else {
        int idx = (b - XBLK) * 256 + threadIdx.x;  // over O*K/4
        int o = idx >> 10;
        int k = (idx & 1023) << 2;
        float4 v = ((const float4*)w)[idx];
        float sc = (k < NNON) ? scales[(size_t)o * NNON + ((k >> 7) << 7)] : keep[o];
        ushort4 r;
        r.x = f2bf(v.x * sc); r.y = f2bf(v.y * sc);
        r.z = f2bf(v.z * sc); r.w = f2bf(v.w * sc);
        ((ushort4*)B)[idx] = r;
    }
}

// NT GEMM: A [M,K] bf16, B [N,K] bf16 (B^T layout), C [M,N] f32.
// 128x128 tile, BK=64, 4 waves 2x2, each wave 4x4 of 16x16x32 MFMAs x2 ksteps.
// R5 change: A-frags come straight from GLOBAL into VGPRs (coalesced 16B/lane,
// L2/L3-resident, prefetched one K-tile ahead under the MFMA shadow) — A is no
// longer staged in LDS. Only B uses LDS (global_load_lds + XOR swizzle,
// R2-verified conflict-free). LDS traffic/tile-pair: 192 KB -> 96 KB, putting
// the MFMA pipe (1242 cyc) above the LDS pipe (~1130 cyc).
#define BM 128
#define BN 128
#define BK 64

__global__ __launch_bounds__(256) void gemm_bt(const unsigned short* __restrict__ A,
                                               const unsigned short* __restrict__ B,
                                               float* __restrict__ C)
{
    __shared__ unsigned short Bs[BN * BK];   // 16 KB (A not staged)

    const int tid  = threadIdx.x;
    const int wave = tid >> 6;
    const int lane = tid & 63;
    const int quad = lane >> 4;
    const int l16  = lane & 15;
    const int bm = blockIdx.y * BM;
    const int bn = blockIdx.x * BN;
    const int wm = (wave >> 1) * 64;
    const int wn = (wave & 1) * 64;

    const int srow = (lane >> 3);                       // 0..7 within chunk
    const int scol = (((lane & 7) ^ (srow & 7)) << 3);  // swizzled global col
    const int swz  = (l16 & 7);                         // reader-side XOR key

    const unsigned short* Bbase = B + (size_t)(bn + wave * 32 + srow) * K_DIM + scol;
    // A-frag row pointers: lane reads A[bm+wm+i*16+l16][k0 + ks*32 + quad*8]
    const unsigned short* Arow[4];
    #pragma unroll
    for (int i = 0; i < 4; ++i)
        Arow[i] = A + (size_t)(bm + wm + i * 16 + l16) * K_DIM + quad * 8;

    f32x4 acc[4][4];
    #pragma unroll
    for (int i = 0; i < 4; ++i)
        #pragma unroll
        for (int j = 0; j < 4; ++j)
            acc[i][j] = (f32x4){0.f, 0.f, 0.f, 0.f};

    // prologue: stage B tile 0, load A frags tile 0
    #pragma unroll
    for (int c = 0; c < 4; ++c)
        __builtin_amdgcn_global_load_lds(
            (__attribute__((address_space(1))) unsigned int*)(Bbase + (size_t)(c * 8) * K_DIM),
            (__attribute__((address_space(3))) unsigned int*)(&Bs[(wave * 4 + c) * 512]),
            16, 0, 0);
    bf16x8 af[2][4], afn[2][4];
    #pragma unroll
    for (int ks = 0; ks < 2; ++ks)
        #pragma unroll
        for (int i = 0; i < 4; ++i)
            af[ks][i] = *(const bf16x8*)(Arow[i] + ks * 32);
    __syncthreads();   // vmcnt(0): B tile 0 resident

    for (int k0 = 0; k0 < K_DIM; k0 += BK) {
        // B fragments from LDS for tile k0
        bf16x8 bfr[2][4];
        #pragma unroll
        for (int ks = 0; ks < 2; ++ks)
            #pragma unroll
            for (int j = 0; j < 4; ++j)
                bfr[ks][j] = *(const bf16x8*)(&Bs[(wn + j * 16 + l16) * BK + (((ks * 4 + quad) ^ swz) << 3)]);
        __syncthreads();   // all waves done reading Bs

        // issue next tile's B staging + A frag prefetch (land under MFMA shadow)
        const size_t knxt = (k0 + BK < K_DIM) ? (size_t)(k0 + BK) : (size_t)k0;
        #pragma unroll
        for (int c = 0; c < 4; ++c)
            __builtin_amdgcn_global_load_lds(
                (__attribute__((address_space(1))) unsigned int*)(Bbase + (size_t)(c * 8) * K_DIM + knxt),
                (__attribute__((address_space(3))) unsigned int*)(&Bs[(wave * 4 + c) * 512]),
                16, 0, 0);
        #pragma unroll
        for (int ks = 0; ks < 2; ++ks)
            #pragma unroll
            for (int i = 0; i < 4; ++i)
                afn[ks][i] = *(const bf16x8*)(Arow[i] + knxt + ks * 32);

        #pragma unroll
        for (int ks = 0; ks < 2; ++ks)
            #pragma unroll
            for (int i = 0; i < 4; ++i)
                #pragma unroll
                for (int j = 0; j < 4; ++j)
                    acc[i][j] = __builtin_amdgcn_mfma_f32_16x16x32_bf16(af[ks][i], bfr[ks][j], acc[i][j], 0, 0, 0);

        #pragma unroll
        for (int ks = 0; ks < 2; ++ks)
            #pragma unroll
            for (int i = 0; i < 4; ++i)
                af[ks][i] = afn[ks][i];

        __syncthreads();   // vmcnt(0) drain: next B tile resident
    }

    // C/D layout (m89-verified): col = lane&15, row = quad*4 + reg
    #pragma unroll
    for (int i = 0; i < 4; ++i)
        #pragma unroll
        for (int j = 0; j < 4; ++j) {
            const int col = bn + wn + j * 16 + l16;
            #pragma unroll
            for (int r = 0; r < 4; ++r) {
                const int row = bm + wm + i * 16 + quad * 4 + r;
                C[(size_t)row * O_DIM + col] = acc[i][j][r];
            }
        }
}

extern "C" void kernel_launch(void* const* d_in, const int* in_sizes, int n_in,
                              void* d_out, int out_size, void* d_ws, size_t ws_size,
                              hipStream_t stream) {
    const float* x      = (const float*)d_in[0];
    const float* weight = (const float*)d_in[1];  // [O, K]
    const float* scales = (const float*)d_in[2];  // [O, NNON]
    const float* keep   = (const float*)d_in[3];  // [O, 1]
    const float* sc_lo  = (const float*)d_in[4];  // [S, NB]
    const float* sc_hi  = (const float*)d_in[5];  // [S, 1]
    // d_in[6], d_in[7] (inp_base_lo/hi) unused by reference

    // workspace: A' 16 MB @ 0, B' 32 MB @ 16 MB (needs 48 MB of d_ws)
    unsigned short* A = (unsigned short*)d_ws;
    unsigned short* B = A + (size_t)S_DIM * K_DIM;

    prepass<<<XBLK + WBLK, 256, 0, stream>>>(x, sc_lo, sc_hi, weight, scales, keep, A, B);

    dim3 grid(O_DIM / BN, S_DIM / BM);
    gemm_bt<<<grid, 256, 0, stream>>>(A, B, (float*)d_out);
}

// Round 6
// 242.869 us; speedup vs baseline: 1.3280x; 1.3280x over previous
//
#include <hip/hip_runtime.h>

#define S_DIM 2048
#define K_DIM 4096
#define O_DIM 4096
#define NNON  3968   // H - KEEPER
#define NB    31     // low-precision blocks

#define XBLK 8192    // scale_x segment blocks:  S*K/4/256
#define WBLK 16384   // scale_w segment blocks:  O*K/4/256

typedef __bf16 bf16x8 __attribute__((ext_vector_type(8)));
typedef float  f32x4  __attribute__((ext_vector_type(4)));

__device__ __forceinline__ unsigned short f2bf(float f) {
    union { float f; unsigned u; } v; v.f = f;
    unsigned r = v.u + 0x7FFFu + ((v.u >> 16) & 1u);   // round-to-nearest-even
    return (unsigned short)(r >> 16);
}

// One fused prepass launch, two block-uniform segments:
//   [0, XBLK)           A'[s,k] = bf16(x * sc_lo/hi)
//   [XBLK, XBLK+WBLK)   B'[o,k] = bf16(w * scales/keep)
__global__ __launch_bounds__(256) void prepass(const float* __restrict__ x,
                                               const float* __restrict__ sc_lo,
                                               const float* __restrict__ sc_hi,
                                               const float* __restrict__ w,
                                               const float* __restrict__ scales,
                                               const float* __restrict__ keep,
                                               unsigned short* __restrict__ A,
                                               unsigned short* __restrict__ B)
{
    const int b = blockIdx.x;
    if (b < XBLK) {
        int idx = b * 256 + threadIdx.x;           // over S*K/4, K/4 = 1024
        int s = idx >> 10;
        int k = (idx & 1023) << 2;                 // 4 elems never straddle a 128-block
        float4 v = ((const float4*)x)[idx];
        float sc = (k < NNON) ? sc_lo[s * NB + (k >> 7)] : sc_hi[s];
        ushort4 o;
        o.x = f2bf(v.x * sc); o.y = f2bf(v.y * sc);
        o.z = f2bf(v.z * sc); o.w = f2bf(v.w * sc);
        ((ushort4*)A)[idx] = o;
    } else {
        int idx = (b - XBLK) * 256 + threadIdx.x;  // over O*K/4
        int o = idx >> 10;
        int k = (idx & 1023) << 2;
        float4 v = ((const float4*)w)[idx];
        float sc = (k < NNON) ? scales[(size_t)o * NNON + ((k >> 7) << 7)] : keep[o];
        ushort4 r;
        r.x = f2bf(v.x * sc); r.y = f2bf(v.y * sc);
        r.z = f2bf(v.z * sc); r.w = f2bf(v.w * sc);
        ((ushort4*)B)[idx] = r;
    }
}

// NT GEMM: A [M,K] bf16, B [N,K] bf16 (B^T layout), C [M,N] f32.
// R6: R4 structure (all global traffic on the global_load_lds DMA path —
// R5's register A-path regressed 2x) with BK=128: halves the number of
// barrier+vmcnt(0) drain events per K. 64 KB LDS/block is free because the
// grid (512 blocks) caps us at 2 blocks/CU anyway (m132's BK=128 loss was
// occupancy-driven; doesn't apply here). __launch_bounds__(256,2) budgets
// 256 regs/wave for the 128 live frag VGPRs + 64 acc.
// Pipeline per tile: [ds_read 32 frags ; barrier ; DMA tile k+1 ; MFMA x64 ;
// barrier w/ vmcnt(0) drain].
// LDS XOR swizzle (16-chunk generalization of the R2-verified scheme):
// 16B chunk at logical (row, q) stored at slot q ^ (row & 15); applied on the
// global source column during staging, un-permuted on ds_read (key = l16).
#define BM 128
#define BN 128
#define BK 128

__global__ __launch_bounds__(256, 2) void gemm_bt(const unsigned short* __restrict__ A,
                                                  const unsigned short* __restrict__ B,
                                                  float* __restrict__ C)
{
    __shared__ unsigned short As[BM * BK];   // 32 KB
    __shared__ unsigned short Bs[BN * BK];   // 32 KB

    const int tid  = threadIdx.x;
    const int wave = tid >> 6;
    const int lane = tid & 63;
    const int quad = lane >> 4;
    const int l16  = lane & 15;
    const int bm = blockIdx.y * BM;
    const int bn = blockIdx.x * BN;
    const int wm = (wave >> 1) * 64;
    const int wn = (wave & 1) * 64;

    const int srow4 = lane >> 4;   // row within a 4-row staging chunk
    const int c16   = lane & 15;   // stored 16B-chunk slot

    // global row bases (include srow4); inst c adds c*4 rows
    const unsigned short* Ab = A + (size_t)(bm + wave * 32 + srow4) * K_DIM;
    const unsigned short* Bb = B + (size_t)(bn + wave * 32 + srow4) * K_DIM;

    f32x4 acc[4][4];
    #pragma unroll
    for (int i = 0; i < 4; ++i)
        #pragma unroll
        for (int j = 0; j < 4; ++j)
            acc[i][j] = (f32x4){0.f, 0.f, 0.f, 0.f};

    // stage one BK=128 tile: per wave 8 A-chunks + 8 B-chunks of 4 rows x 256 B.
    // dest = wave-uniform base + lane*16 (row = +lane>>4, slot = lane&15);
    // source col chunk = slot ^ (row & 15)  -> swizzled store.
    auto stage = [&](int k0) {
        #pragma unroll
        for (int c = 0; c < 8; ++c) {
            const int gc = ((c16 ^ ((c * 4 + srow4) & 15)) << 3);
            __builtin_amdgcn_global_load_lds(
                (__attribute__((address_space(1))) unsigned int*)(Ab + (size_t)(c * 4) * K_DIM + k0 + gc),
                (__attribute__((address_space(3))) unsigned int*)(&As[(wave * 32 + c * 4) * BK]),
                16, 0, 0);
            __builtin_amdgcn_global_load_lds(
                (__attribute__((address_space(1))) unsigned int*)(Bb + (size_t)(c * 4) * K_DIM + k0 + gc),
                (__attribute__((address_space(3))) unsigned int*)(&Bs[(wave * 32 + c * 4) * BK]),
                16, 0, 0);
        }
    };

    stage(0);
    __syncthreads();   // vmcnt(0): tile 0 resident

    for (int k0 = 0; k0 < K_DIM; k0 += BK) {
        // LDS -> register fragments for tile k0 (all 4 ksteps up front;
        // reader un-swizzle: stored slot q ^ l16 holds logical chunk q)
        bf16x8 af[4][4], bfr[4][4];
        #pragma unroll
        for (int ks = 0; ks < 4; ++ks) {
            #pragma unroll
            for (int i = 0; i < 4; ++i)
                af[ks][i] = *(const bf16x8*)(&As[(wm + i * 16 + l16) * BK + (((ks * 4 + quad) ^ l16) << 3)]);
            #pragma unroll
            for (int j = 0; j < 4; ++j)
                bfr[ks][j] = *(const bf16x8*)(&Bs[(wn + j * 16 + l16) * BK + (((ks * 4 + quad) ^ l16) << 3)]);
        }
        __syncthreads();   // all waves done reading LDS

        // issue next tile's DMA; the 64 MFMAs below run in its latency shadow
        if (k0 + BK < K_DIM)
            stage(k0 + BK);

        #pragma unroll
        for (int ks = 0; ks < 4; ++ks)
            #pragma unroll
            for (int i = 0; i < 4; ++i)
                #pragma unroll
                for (int j = 0; j < 4; ++j)
                    acc[i][j] = __builtin_amdgcn_mfma_f32_16x16x32_bf16(af[ks][i], bfr[ks][j], acc[i][j], 0, 0, 0);

        __syncthreads();   // vmcnt(0) drain: next tile resident
    }

    // C/D layout (m89-verified): col = lane&15, row = quad*4 + reg
    #pragma unroll
    for (int i = 0; i < 4; ++i)
        #pragma unroll
        for (int j = 0; j < 4; ++j) {
            const int col = bn + wn + j * 16 + l16;
            #pragma unroll
            for (int r = 0; r < 4; ++r) {
                const int row = bm + wm + i * 16 + quad * 4 + r;
                C[(size_t)row * O_DIM + col] = acc[i][j][r];
            }
        }
}

extern "C" void kernel_launch(void* const* d_in, const int* in_sizes, int n_in,
                              void* d_out, int out_size, void* d_ws, size_t ws_size,
                              hipStream_t stream) {
    const float* x      = (const float*)d_in[0];
    const float* weight = (const float*)d_in[1];  // [O, K]
    const float* scales = (const float*)d_in[2];  // [O, NNON]
    const float* keep   = (const float*)d_in[3];  // [O, 1]
    const float* sc_lo  = (const float*)d_in[4];  // [S, NB]
    const float* sc_hi  = (const float*)d_in[5];  // [S, 1]
    // d_in[6], d_in[7] (inp_base_lo/hi) unused by reference

    // workspace: A' 16 MB @ 0, B' 32 MB @ 16 MB (needs 48 MB of d_ws)
    unsigned short* A = (unsigned short*)d_ws;
    unsigned short* B = A + (size_t)S_DIM * K_DIM;

    prepass<<<XBLK + WBLK, 256, 0, stream>>>(x, sc_lo, sc_hi, weight, scales, keep, A, B);

    dim3 grid(O_DIM / BN, S_DIM / BM);
    gemm_bt<<<grid, 256, 0, stream>>>(A, B, (float*)d_out);
}